// Round 2
// baseline (78.625 us; speedup 1.0000x reference)
//
#include <hip/hip_runtime.h>
#include <math.h>

#define NN 1024
#define NE 8192

struct c32 { float x, y; };
__device__ __forceinline__ c32 cmul(c32 a, c32 b) { return {a.x*b.x - a.y*b.y, a.x*b.y + a.y*b.x}; }
__device__ __forceinline__ c32 cadd(c32 a, c32 b) { return {a.x + b.x, a.y + b.y}; }

// PennyLane Rot(phi,theta,omega) = RZ(om) RY(th) RZ(phi)
__device__ __forceinline__ void rot2(const float* __restrict__ t3, c32 A[2][2]) {
  float phi = t3[0], th = t3[1], om = t3[2];
  float s, c;   sincosf(0.5f * th, &s, &c);
  float sa, ca; sincosf(0.5f * (phi + om), &sa, &ca);
  float sb, cb; sincosf(0.5f * (phi - om), &sb, &cb);
  A[0][0] = {  ca * c, -sa * c };
  A[0][1] = { -cb * s, -sb * s };
  A[1][0] = {  cb * s, -sb * s };
  A[1][1] = {  ca * c,  sa * c };
}

// ---------------- kernel 1: one-hot index extraction + zero mi/mo ----------------
__global__ void k_extract(const float* __restrict__ Ri, const float* __restrict__ Ro,
                          int* __restrict__ idx_i, int* __restrict__ idx_o,
                          float* __restrict__ mimo /* 2*NN*4 floats, zeroed here */) {
  const int per = NN * NE / 4;               // float4 per matrix
  int tid    = blockIdx.x * blockDim.x + threadIdx.x;
  int stride = gridDim.x * blockDim.x;
  if (tid < (2 * NN * 4) / 4) ((float4*)mimo)[tid] = make_float4(0.f, 0.f, 0.f, 0.f);
  for (int t = tid; t < 2 * per; t += stride) {
    bool first = (t < per);
    const float4* src = first ? (const float4*)Ri : (const float4*)Ro;
    int* dst          = first ? idx_i : idx_o;
    int q = first ? t : t - per;
    float4 v = src[q];
    if (v.x != 0.f || v.y != 0.f || v.z != 0.f || v.w != 0.f) {
      int base = q * 4;
      int n = base >> 13;            // / NE
      int k = base & (NE - 1);       // % NE
      if (v.x != 0.f) dst[k + 0] = n;
      if (v.y != 0.f) dst[k + 1] = n;
      if (v.z != 0.f) dst[k + 2] = n;
      if (v.w != 0.f) dst[k + 3] = n;
    }
  }
}

// ---------------- kernel 2: edge-parallel message aggregation ----------------
__global__ void k_edges(const float* __restrict__ X, const float* __restrict__ e,
                        const int* __restrict__ idx_i, const int* __restrict__ idx_o,
                        float* __restrict__ mi, float* __restrict__ mo) {
  int k = blockIdx.x * blockDim.x + threadIdx.x;
  if (k >= NE) return;
  int ni = idx_i[k], no = idx_o[k];
  float w = e[k];
  float4 xo = ((const float4*)X)[no];
  float4 xi = ((const float4*)X)[ni];
  atomicAdd(&mi[ni * 4 + 0], w * xo.x);
  atomicAdd(&mi[ni * 4 + 1], w * xo.y);
  atomicAdd(&mi[ni * 4 + 2], w * xo.z);
  atomicAdd(&mi[ni * 4 + 3], w * xo.w);
  atomicAdd(&mo[no * 4 + 0], w * xi.x);
  atomicAdd(&mo[no * 4 + 1], w * xi.y);
  atomicAdd(&mo[no * 4 + 2], w * xi.z);
  atomicAdd(&mo[no * 4 + 3], w * xi.w);
}

// ---------------- kernel 3: brute-force statevector circuit (reference mirror) ----------------
// One workgroup per node. 4096 complex amplitudes in LDS. Wire 0 = MSB (bit 11).
__device__ __forceinline__ void apply1(float2* __restrict__ S, int tid, int b, const c32 (*U)[2]) {
  c32 U00 = U[0][0], U01 = U[0][1], U10 = U[1][0], U11 = U[1][1];
  int mask = (1 << b) - 1;
  for (int t = tid; t < 2048; t += 256) {
    int i0 = ((t & ~mask) << 1) | (t & mask);
    int i1 = i0 | (1 << b);
    float2 av = S[i0], bv = S[i1];
    c32 a = {av.x, av.y}, c = {bv.x, bv.y};
    c32 r0 = cadd(cmul(U00, a), cmul(U01, c));
    c32 r1 = cadd(cmul(U10, a), cmul(U11, c));
    S[i0] = {r0.x, r0.y};
    S[i1] = {r1.x, r1.y};
  }
}

__global__ void __launch_bounds__(256) k_sv(const float* __restrict__ X,
                                            const float* __restrict__ theta,
                                            const float* __restrict__ mi,
                                            const float* __restrict__ mo,
                                            float* __restrict__ out) {
  __shared__ float2 S[4096];
  __shared__ c32 R[23][2][2];
  __shared__ float red[256];
  const int tid = threadIdx.x;
  const int n = blockIdx.x;

  if (tid < 23) {
    c32 A[2][2];
    rot2(theta + 3 * tid, A);
    R[tid][0][0] = A[0][0]; R[tid][0][1] = A[0][1];
    R[tid][1][0] = A[1][0]; R[tid][1][1] = A[1][1];
  }

  // Angles and product-state init (the 12 RY gates applied analytically to |0...0>)
  float4 miv = ((const float4*)mi)[n];
  float4 mov = ((const float4*)mo)[n];
  float4 xv  = ((const float4*)X)[n];
  float ang[12] = { miv.x, miv.y, miv.z, miv.w, mov.x, mov.y, mov.z, mov.w, xv.x, xv.y, xv.z, xv.w };
  float cw[12], sw[12];
  #pragma unroll
  for (int w = 0; w < 12; w++) sincosf(0.5f * ang[w], &sw[w], &cw[w]);

  for (int j = 0; j < 16; j++) {
    int i = tid + 256 * j;
    float amp = 1.f;
    #pragma unroll
    for (int w = 0; w < 12; w++)
      amp *= ((i >> (11 - w)) & 1) ? sw[w] : cw[w];
    S[i] = {amp, 0.f};
  }
  __syncthreads();

  const int BW1[11] = {0, 2, 4, 6, 8, 10, 1, 5, 9, 2, 5};
  const int BW2[11] = {1, 3, 5, 7, 9, 11, 2, 6, 10, 5, 9};
  const int BC [11] = {0, 3, 4, 7, 8, 11, 1, 6, 10, 2, 5};
  const int BT [11] = {1, 2, 5, 6, 9, 10, 2, 5, 9, 5, 9};

  for (int k = 0; k < 11; k++) {
    apply1(S, tid, 11 - BW1[k], R[2 * k]);     __syncthreads();
    apply1(S, tid, 11 - BW2[k], R[2 * k + 1]); __syncthreads();
    // CNOT(BC[k] -> BT[k]): swap pairs where control bit = 1 along the target bit.
    int cb = 11 - BC[k], tb = 11 - BT[k];
    int lo = cb < tb ? cb : tb, hi = cb < tb ? tb : cb;
    int lmask = (1 << lo) - 1, hmask = (1 << hi) - 1;
    for (int t = tid; t < 1024; t += 256) {
      int x = ((t & ~lmask) << 1) | (t & lmask);
      x = ((x & ~hmask) << 1) | (x & hmask);
      int i0 = x | (1 << cb);       // control=1, target=0
      int i1 = i0 | (1 << tb);
      float2 a = S[i0], b = S[i1];
      S[i0] = b; S[i1] = a;
    }
    __syncthreads();
  }
  // final Rot on wire 4 (theta[66:69]) — applied for exact fidelity to reference
  apply1(S, tid, 11 - 4, R[22]);
  __syncthreads();

  // <Z on wire 9>: sign by bit value 4
  float part = 0.f;
  for (int j = 0; j < 16; j++) {
    int i = tid + 256 * j;
    float2 v = S[i];
    float p = v.x * v.x + v.y * v.y;
    part += ((i >> 2) & 1) ? -p : p;
  }
  red[tid] = part;
  __syncthreads();
  for (int s2 = 128; s2 > 0; s2 >>= 1) {
    if (tid < s2) red[tid] += red[tid + s2];
    __syncthreads();
  }
  if (tid == 0) out[n] = 3.14159265358979f * (1.f - red[0]);
}

extern "C" void kernel_launch(void* const* d_in, const int* in_sizes, int n_in,
                              void* d_out, int out_size, void* d_ws, size_t ws_size,
                              hipStream_t stream) {
  (void)in_sizes; (void)n_in; (void)out_size; (void)ws_size;
  const float* X     = (const float*)d_in[0];
  const float* e     = (const float*)d_in[1];
  const float* Ri    = (const float*)d_in[2];
  const float* Ro    = (const float*)d_in[3];
  const float* theta = (const float*)d_in[4];
  float* out = (float*)d_out;

  char* ws = (char*)d_ws;
  int*   idx_i = (int*)(ws);                   // 8192 ints
  int*   idx_o = (int*)(ws + 32768);           // 8192 ints
  float* mi    = (float*)(ws + 65536);         // 1024x4 f32
  float* mo    = (float*)(ws + 65536 + 16384); // 1024x4 f32 (contiguous with mi)

  hipLaunchKernelGGL(k_extract, dim3(4096), dim3(256), 0, stream, Ri, Ro, idx_i, idx_o, mi);
  hipLaunchKernelGGL(k_edges,   dim3(NE / 256), dim3(256), 0, stream, X, e, idx_i, idx_o, mi, mo);
  hipLaunchKernelGGL(k_sv,      dim3(NN), dim3(256), 0, stream, X, theta, mi, mo, out);
}

// Round 3
// 36.428 us; speedup vs baseline: 2.1584x; 2.1584x over previous
//
#include <hip/hip_runtime.h>
#include <math.h>

#define NN 1024
#define NE 8192

struct c32 { float x, y; };
__device__ __forceinline__ c32 cmul(c32 a, c32 b)  { return {a.x*b.x - a.y*b.y, a.x*b.y + a.y*b.x}; }
__device__ __forceinline__ c32 cmulc(c32 a, c32 b) { return {a.x*b.x + a.y*b.y, a.y*b.x - a.x*b.y}; } // a*conj(b)
__device__ __forceinline__ c32 cadd(c32 a, c32 b)  { return {a.x + b.x, a.y + b.y}; }

// PennyLane Rot(phi,theta,omega) = RZ(om) RY(th) RZ(phi)  [verified round 1]
__device__ __forceinline__ void rot2(const float* __restrict__ t3, c32 A[2][2]) {
  float phi = t3[0], th = t3[1], om = t3[2];
  float s, c;   sincosf(0.5f * th, &s, &c);
  float sa, ca; sincosf(0.5f * (phi + om), &sa, &ca);
  float sb, cb; sincosf(0.5f * (phi - om), &sb, &cb);
  A[0][0] = {  ca * c, -sa * c };
  A[0][1] = { -cb * s, -sb * s };
  A[1][0] = {  cb * s, -sb * s };
  A[1][1] = {  ca * c,  sa * c };
}

// ---------------- kernel 1: one-hot index extraction + zero mi/mo [verified] ----------------
__global__ void k_extract(const float* __restrict__ Ri, const float* __restrict__ Ro,
                          int* __restrict__ idx_i, int* __restrict__ idx_o,
                          float* __restrict__ mimo) {
  const int per = NN * NE / 4;
  int tid    = blockIdx.x * blockDim.x + threadIdx.x;
  int stride = gridDim.x * blockDim.x;
  if (tid < (2 * NN * 4) / 4) ((float4*)mimo)[tid] = make_float4(0.f, 0.f, 0.f, 0.f);
  for (int t = tid; t < 2 * per; t += stride) {
    bool first = (t < per);
    const float4* src = first ? (const float4*)Ri : (const float4*)Ro;
    int* dst          = first ? idx_i : idx_o;
    int q = first ? t : t - per;
    float4 v = src[q];
    if (v.x != 0.f || v.y != 0.f || v.z != 0.f || v.w != 0.f) {
      int base = q * 4;
      int n = base >> 13;
      int k = base & (NE - 1);
      if (v.x != 0.f) dst[k + 0] = n;
      if (v.y != 0.f) dst[k + 1] = n;
      if (v.z != 0.f) dst[k + 2] = n;
      if (v.w != 0.f) dst[k + 3] = n;
    }
  }
}

// ---------------- kernel 2: edge-parallel message aggregation [verified] ----------------
__global__ void k_edges(const float* __restrict__ X, const float* __restrict__ e,
                        const int* __restrict__ idx_i, const int* __restrict__ idx_o,
                        float* __restrict__ mi, float* __restrict__ mo) {
  int k = blockIdx.x * blockDim.x + threadIdx.x;
  if (k >= NE) return;
  int ni = idx_i[k], no = idx_o[k];
  float w = e[k];
  float4 xo = ((const float4*)X)[no];
  float4 xi = ((const float4*)X)[ni];
  atomicAdd(&mi[ni * 4 + 0], w * xo.x);
  atomicAdd(&mi[ni * 4 + 1], w * xo.y);
  atomicAdd(&mi[ni * 4 + 2], w * xo.z);
  atomicAdd(&mi[ni * 4 + 3], w * xo.w);
  atomicAdd(&mo[no * 4 + 0], w * xi.x);
  atomicAdd(&mo[no * 4 + 1], w * xi.y);
  atomicAdd(&mo[no * 4 + 2], w * xi.z);
  atomicAdd(&mo[no * 4 + 3], w * xi.w);
}

// ---------------- kernel 3: factorized statevector ----------------
// psi_A = wires 0..7 (256 amps, bit = 7-w), psi_B = wires 8..11 (16 amps, bit = 11-w).
// Gate application code identical in structure to the round-1 verified kernel.
__device__ __forceinline__ void gate1(float2* __restrict__ S, int tid, int pairs, int b,
                                      const c32 (*U)[2]) {
  c32 U00 = U[0][0], U01 = U[0][1], U10 = U[1][0], U11 = U[1][1];
  int mask = (1 << b) - 1;
  for (int t = tid; t < pairs; t += 64) {
    int i0 = ((t & ~mask) << 1) | (t & mask);
    int i1 = i0 | (1 << b);
    float2 av = S[i0], bv = S[i1];
    c32 a = {av.x, av.y}, c = {bv.x, bv.y};
    c32 r0 = cadd(cmul(U00, a), cmul(U01, c));
    c32 r1 = cadd(cmul(U10, a), cmul(U11, c));
    S[i0] = {r0.x, r0.y};
    S[i1] = {r1.x, r1.y};
  }
}

__device__ __forceinline__ void cnotg(float2* __restrict__ S, int tid, int quarter, int cb, int tb) {
  int lo = cb < tb ? cb : tb, hi = cb < tb ? tb : cb;
  int lmask = (1 << lo) - 1, hmask = (1 << hi) - 1;
  for (int t = tid; t < quarter; t += 64) {
    int x = ((t & ~lmask) << 1) | (t & lmask);
    x = ((x & ~hmask) << 1) | (x & hmask);
    int i0 = x | (1 << cb);       // control=1, target=0
    int i1 = i0 | (1 << tb);
    float2 a = S[i0], b = S[i1];
    S[i0] = b; S[i1] = a;
  }
}

__global__ void __launch_bounds__(64) k_sv2(const float* __restrict__ X,
                                            const float* __restrict__ theta,
                                            const float* __restrict__ mi,
                                            const float* __restrict__ mo,
                                            float* __restrict__ out) {
  __shared__ float2 SA[256];
  __shared__ float2 SB[16];
  __shared__ c32 R[23][2][2];
  const int tid = threadIdx.x;
  const int n = blockIdx.x;

  if (tid < 23) {
    c32 A[2][2];
    rot2(theta + 3 * tid, A);
    R[tid][0][0] = A[0][0]; R[tid][0][1] = A[0][1];
    R[tid][1][0] = A[1][0]; R[tid][1][1] = A[1][1];
  }

  float4 miv = ((const float4*)mi)[n];
  float4 mov = ((const float4*)mo)[n];
  float4 xv  = ((const float4*)X)[n];
  float ang[12] = { miv.x, miv.y, miv.z, miv.w, mov.x, mov.y, mov.z, mov.w, xv.x, xv.y, xv.z, xv.w };
  float cw[12], sw[12];
  #pragma unroll
  for (int w = 0; w < 12; w++) sincosf(0.5f * ang[w], &sw[w], &cw[w]);

  // product-state init (12 RY gates analytic)
  #pragma unroll
  for (int j = 0; j < 4; j++) {
    int i = tid + 64 * j;
    float amp = 1.f;
    #pragma unroll
    for (int w = 0; w < 8; w++) amp *= ((i >> (7 - w)) & 1) ? sw[w] : cw[w];
    SA[i] = {amp, 0.f};
  }
  if (tid < 16) {
    float amp = 1.f;
    #pragma unroll
    for (int w = 8; w < 12; w++) amp *= ((tid >> (11 - w)) & 1) ? sw[w] : cw[w];
    SB[tid] = {amp, 0.f};
  }
  __syncthreads();

  // A-blocks and B-blocks in reference order (disjoint groups commute).
  // block0 (0,1) c0->t1
  gate1(SA, tid, 128, 7, R[0]);  __syncthreads();
  gate1(SA, tid, 128, 6, R[1]);  __syncthreads();
  cnotg(SA, tid, 64, 7, 6);      __syncthreads();
  // block1 (2,3) c3->t2
  gate1(SA, tid, 128, 5, R[2]);  __syncthreads();
  gate1(SA, tid, 128, 4, R[3]);  __syncthreads();
  cnotg(SA, tid, 64, 4, 5);      __syncthreads();
  // block2 (4,5) c4->t5
  gate1(SA, tid, 128, 3, R[4]);  __syncthreads();
  gate1(SA, tid, 128, 2, R[5]);  __syncthreads();
  cnotg(SA, tid, 64, 3, 2);      __syncthreads();
  // block3 (6,7) c7->t6
  gate1(SA, tid, 128, 1, R[6]);  __syncthreads();
  gate1(SA, tid, 128, 0, R[7]);  __syncthreads();
  cnotg(SA, tid, 64, 0, 1);      __syncthreads();
  // block4 (8,9) c8->t9  [B]
  gate1(SB, tid, 8, 3, R[8]);    __syncthreads();
  gate1(SB, tid, 8, 2, R[9]);    __syncthreads();
  cnotg(SB, tid, 4, 3, 2);       __syncthreads();
  // block5 (10,11) c11->t10  [B]
  gate1(SB, tid, 8, 1, R[10]);   __syncthreads();
  gate1(SB, tid, 8, 0, R[11]);   __syncthreads();
  cnotg(SB, tid, 4, 0, 1);       __syncthreads();
  // block6 (1,2) c1->t2
  gate1(SA, tid, 128, 6, R[12]); __syncthreads();
  gate1(SA, tid, 128, 5, R[13]); __syncthreads();
  cnotg(SA, tid, 64, 6, 5);      __syncthreads();
  // block7 (5,6) c6->t5
  gate1(SA, tid, 128, 2, R[14]); __syncthreads();
  gate1(SA, tid, 128, 1, R[15]); __syncthreads();
  cnotg(SA, tid, 64, 1, 2);      __syncthreads();
  // block8 (9,10) c10->t9  [B]
  gate1(SB, tid, 8, 2, R[16]);   __syncthreads();
  gate1(SB, tid, 8, 1, R[17]);   __syncthreads();
  cnotg(SB, tid, 4, 1, 2);       __syncthreads();
  // block9 (2,5) c2->t5
  gate1(SA, tid, 128, 5, R[18]); __syncthreads();
  gate1(SA, tid, 128, 2, R[19]); __syncthreads();
  cnotg(SA, tid, 64, 5, 2);      __syncthreads();
  // final Rot on wire 4 (commutes with block 10; applied to psi_A for exact reference mirror)
  gate1(SA, tid, 128, 3, R[22]); __syncthreads();

  // rho5: reduced density of wire 5 (bit 2) from psi_A. 128 'other' states, 2 per lane.
  float p00 = 0.f, p11 = 0.f; c32 p01 = {0.f, 0.f};
  #pragma unroll
  for (int m = 0; m < 2; m++) {
    int ao = tid + 64 * m;
    int i0 = ((ao & ~3) << 1) | (ao & 3);
    int i1 = i0 | 4;
    float2 a0 = SA[i0], a1 = SA[i1];
    p00 += a0.x * a0.x + a0.y * a0.y;
    p11 += a1.x * a1.x + a1.y * a1.y;
    p01 = cadd(p01, cmulc({a0.x, a0.y}, {a1.x, a1.y}));
  }
  #pragma unroll
  for (int m = 1; m < 64; m <<= 1) {
    p00 += __shfl_xor(p00, m, 64);
    p11 += __shfl_xor(p11, m, 64);
    p01.x += __shfl_xor(p01.x, m, 64);
    p01.y += __shfl_xor(p01.y, m, 64);
  }

  // rho9: reduced density of wire 9 (bit 2) from psi_B — redundant on all lanes (LDS broadcast).
  float q00 = 0.f, q11 = 0.f; c32 q01 = {0.f, 0.f};
  #pragma unroll
  for (int ao = 0; ao < 8; ao++) {
    int i0 = ((ao & ~3) << 1) | (ao & 3);
    int i1 = i0 | 4;
    float2 b0 = SB[i0], b1 = SB[i1];
    q00 += b0.x * b0.x + b0.y * b0.y;
    q11 += b1.x * b1.x + b1.y * b1.y;
    q01 = cadd(q01, cmulc({b0.x, b0.y}, {b1.x, b1.y}));
  }

  // U4 = CNOT(5->9) * (R20 ⊗ R21), wire5 = high bit -> CNOT swaps rows 2,3
  c32 U4[4][4];
  #pragma unroll
  for (int i = 0; i < 2; i++)
    #pragma unroll
    for (int p = 0; p < 2; p++)
      #pragma unroll
      for (int j = 0; j < 2; j++)
        #pragma unroll
        for (int q = 0; q < 2; q++)
          U4[2 * i + p][2 * j + q] = cmul(R[20][i][j], R[21][p][q]);
  #pragma unroll
  for (int c = 0; c < 4; c++) { c32 t = U4[2][c]; U4[2][c] = U4[3][c]; U4[3][c] = t; }

  // z = sum_{a,b} M[a][b] rho5[a5][b5] rho9[a9][b9],  M[a][b] = sum_i s(i9) U4[i][a] conj(U4[i][b])
  c32 rho5[2][2] = { {{p00, 0.f}, p01}, {{p01.x, -p01.y}, {p11, 0.f}} };
  c32 rho9[2][2] = { {{q00, 0.f}, q01}, {{q01.x, -q01.y}, {q11, 0.f}} };
  float z = 0.f;
  #pragma unroll
  for (int a = 0; a < 4; a++)
    #pragma unroll
    for (int b = 0; b < 4; b++) {
      c32 m = {0.f, 0.f};
      #pragma unroll
      for (int i = 0; i < 4; i++) {
        c32 t = cmulc(U4[i][a], U4[i][b]);
        if (i & 1) { m.x -= t.x; m.y -= t.y; } else { m = cadd(m, t); }
      }
      c32 rr = cmul(rho5[a >> 1][b >> 1], rho9[a & 1][b & 1]);
      z += m.x * rr.x - m.y * rr.y;
    }

  if (tid == 0) out[n] = 3.14159265358979f * (1.f - z);
}

extern "C" void kernel_launch(void* const* d_in, const int* in_sizes, int n_in,
                              void* d_out, int out_size, void* d_ws, size_t ws_size,
                              hipStream_t stream) {
  (void)in_sizes; (void)n_in; (void)out_size; (void)ws_size;
  const float* X     = (const float*)d_in[0];
  const float* e     = (const float*)d_in[1];
  const float* Ri    = (const float*)d_in[2];
  const float* Ro    = (const float*)d_in[3];
  const float* theta = (const float*)d_in[4];
  float* out = (float*)d_out;

  char* ws = (char*)d_ws;
  int*   idx_i = (int*)(ws);
  int*   idx_o = (int*)(ws + 32768);
  float* mi    = (float*)(ws + 65536);
  float* mo    = (float*)(ws + 65536 + 16384);

  hipLaunchKernelGGL(k_extract, dim3(4096), dim3(256), 0, stream, Ri, Ro, idx_i, idx_o, mi);
  hipLaunchKernelGGL(k_edges,   dim3(NE / 256), dim3(256), 0, stream, X, e, idx_i, idx_o, mi, mo);
  hipLaunchKernelGGL(k_sv2,     dim3(NN), dim3(64), 0, stream, X, theta, mi, mo, out);
}